// Round 1
// baseline (1461.869 us; speedup 1.0000x reference)
//
#include <hip/hip_runtime.h>
#include <hip/hip_bf16.h>

// MLA transformer block on MI355X. Round 1: correct baseline.
// GEMMs: m97 structure (128x128 tile, BK=32, global_load_lds w=16, mfma 16x16x32 bf16).

typedef short bf16x8 __attribute__((ext_vector_type(8)));
typedef float f32x4 __attribute__((ext_vector_type(4)));
typedef unsigned short u16;

#define BM 128
#define BN 128
#define BK 32

__device__ __forceinline__ u16 f2bf(float f) {
  unsigned int u = __builtin_bit_cast(unsigned int, f);
  u += 0x7FFFu + ((u >> 16) & 1u);
  return (u16)(u >> 16);
}

__device__ __forceinline__ void gload_lds16(const void* g, void* l) {
  __builtin_amdgcn_global_load_lds(
      (const __attribute__((address_space(1))) unsigned int*)(uintptr_t)g,
      (__attribute__((address_space(3))) unsigned int*)(unsigned int)(uintptr_t)l,
      16, 0, 0);
}

// ---------------- transpose + f32->bf16 : out[N][K] = (bf16) in[K][N] ------
__global__ __launch_bounds__(256) void k_transpose_bf16(
    const float* __restrict__ in, u16* __restrict__ out, int K, int N) {
  __shared__ float tile[32][33];
  int k0 = blockIdx.x * 32, n0 = blockIdx.y * 32;
  int tx = threadIdx.x & 31, ty = threadIdx.x >> 5;
#pragma unroll
  for (int i = 0; i < 4; ++i) {
    int k = k0 + ty + i * 8, n = n0 + tx;
    tile[ty + i * 8][tx] = (k < K && n < N) ? in[(size_t)k * N + n] : 0.f;
  }
  __syncthreads();
#pragma unroll
  for (int i = 0; i < 4; ++i) {
    int n = n0 + ty + i * 8, k = k0 + tx;
    if (n < N && k < K) out[(size_t)n * K + k] = f2bf(tile[tx][ty + i * 8]);
  }
}

// ---------------- RoPE tables: cos/sin[s][i], i<32 -------------------------
__global__ void k_rope_table(float* __restrict__ cosT, float* __restrict__ sinT) {
  int idx = blockIdx.x * 256 + threadIdx.x;
  if (idx >= 2048 * 32) return;
  int s = idx >> 5, i = idx & 31;
  float inv = exp2f(-(float)i * 0.41524101186092037f); // log2(10000)/32
  float a = (float)s * inv;
  cosT[idx] = cosf(a);
  sinT[idx] = sinf(a);
}

// ---------------- LayerNorm row=2048, out bf16 -----------------------------
__global__ __launch_bounds__(256) void k_ln(const float* __restrict__ x,
                                            const float* __restrict__ w,
                                            const float* __restrict__ b,
                                            u16* __restrict__ out) {
  const int row = blockIdx.x, tid = threadIdx.x;
  const float* xr = x + (size_t)row * 2048;
  float xv[8];
  *(float4*)&xv[0] = ((const float4*)xr)[tid * 2];
  *(float4*)&xv[4] = ((const float4*)xr)[tid * 2 + 1];
  float s = 0.f, ss = 0.f;
#pragma unroll
  for (int j = 0; j < 8; ++j) { s += xv[j]; ss += xv[j] * xv[j]; }
#pragma unroll
  for (int m_ = 32; m_; m_ >>= 1) { s += __shfl_xor(s, m_); ss += __shfl_xor(ss, m_); }
  __shared__ float red[8];
  const int wv = tid >> 6;
  if ((tid & 63) == 0) { red[wv] = s; red[wv + 4] = ss; }
  __syncthreads();
  s = red[0] + red[1] + red[2] + red[3];
  ss = red[4] + red[5] + red[6] + red[7];
  const float mean = s * (1.f / 2048.f);
  const float rs = rsqrtf(ss * (1.f / 2048.f) - mean * mean + 1e-5f);
  float wv8[8], bv8[8];
  *(float4*)&wv8[0] = ((const float4*)w)[tid * 2];
  *(float4*)&wv8[4] = ((const float4*)w)[tid * 2 + 1];
  *(float4*)&bv8[0] = ((const float4*)b)[tid * 2];
  *(float4*)&bv8[4] = ((const float4*)b)[tid * 2 + 1];
  u16 t[8] __attribute__((aligned(16)));
#pragma unroll
  for (int j = 0; j < 8; ++j) t[j] = f2bf((xv[j] - mean) * rs * wv8[j] + bv8[j]);
  *(int4*)&out[(size_t)row * 2048 + tid * 8] = *(int4*)t;
}

// ---------------- RoPE in-place (fp32) -------------------------------------
__global__ void k_rope_q(float* __restrict__ qr, const float* __restrict__ cosT,
                         const float* __restrict__ sinT) {
  int idx = blockIdx.x * 256 + threadIdx.x; // 4096*16*32
  if (idx >= 4096 * 16 * 32) return;
  int i = idx & 31, rest = idx >> 5;
  int h = rest & 15, m = rest >> 4;
  int s = m & 2047;
  float c = cosT[s * 32 + i], sn = sinT[s * 32 + i];
  float* p = qr + (size_t)m * 1024 + h * 64 + i;
  float x0 = p[0], x1 = p[32];
  p[0] = x0 * c - x1 * sn;
  p[32] = x1 * c + x0 * sn;
}

__global__ void k_rope_k(float* __restrict__ kr, const float* __restrict__ cosT,
                         const float* __restrict__ sinT, float* __restrict__ nkv) {
  int idx = blockIdx.x * 256 + threadIdx.x; // 4096*32
  if (idx >= 4096 * 32) return;
  int i = idx & 31, m = idx >> 5;
  int s = m & 2047;
  float c = cosT[s * 32 + i], sn = sinT[s * 32 + i];
  float* p = kr + (size_t)m * 64 + i;
  float x0 = p[0], x1 = p[32];
  float y0 = x0 * c - x1 * sn;
  float y1 = x1 * c + x0 * sn;
  p[0] = y0; p[32] = y1;
  nkv[(size_t)m * 576 + 512 + i] = y0;
  nkv[(size_t)m * 576 + 544 + i] = y1;
}

// ---------------- GEMM: C[M][N] = A[M][K](bf16) * Bt[N][K]^T + bias --------
enum { EP_Q = 0, EP_DKV = 1, EP_KV = 2, EP_RES = 3, EP_GELU = 4 };

template <int EP>
__global__ __launch_bounds__(256) void k_gemm(
    const u16* __restrict__ A, const u16* __restrict__ Bt,
    const float* __restrict__ bias, int K, int Nreal,
    void* out0_, void* out1_, void* out2_, const float* __restrict__ res) {
  __shared__ u16 As[BM * BK];
  __shared__ u16 Bs[BN * BK];
  const int tid = threadIdx.x;
  const int w = tid >> 6, lane = tid & 63;
  const int bm = blockIdx.y * BM, bn = blockIdx.x * BN;
  const int wr = (w >> 1) * 64, wc = (w & 1) * 64;

  const u16* Ag = A + (size_t)(bm + w * 32 + (lane >> 2)) * K + (lane & 3) * 8;
  const u16* Bg = Bt + (size_t)(bn + w * 32 + (lane >> 2)) * K + (lane & 3) * 8;
  char* lA = (char*)As + w * 2048;
  char* lB = (char*)Bs + w * 2048;

  f32x4 acc[4][4] = {};
  for (int k0 = 0; k0 < K; k0 += BK) {
    __syncthreads();
    gload_lds16(Ag, lA);
    gload_lds16(Ag + 16 * K, lA + 1024);
    gload_lds16(Bg, lB);
    gload_lds16(Bg + 16 * K, lB + 1024);
    Ag += BK; Bg += BK;
    __syncthreads();
    const int ka = (lane >> 4) * 8;
    const int lc = lane & 15;
    bf16x8 av[4], bv[4];
#pragma unroll
    for (int i = 0; i < 4; ++i) av[i] = *(const bf16x8*)&As[(wr + i * 16 + lc) * BK + ka];
#pragma unroll
    for (int j = 0; j < 4; ++j) bv[j] = *(const bf16x8*)&Bs[(wc + j * 16 + lc) * BK + ka];
#pragma unroll
    for (int i = 0; i < 4; ++i)
#pragma unroll
      for (int j = 0; j < 4; ++j)
        acc[i][j] = __builtin_amdgcn_mfma_f32_16x16x32_bf16(av[i], bv[j], acc[i][j], 0, 0, 0);
  }

  const int lr = (lane >> 4) * 4, lc = lane & 15;
#pragma unroll
  for (int i = 0; i < 4; ++i) {
#pragma unroll
    for (int j = 0; j < 4; ++j) {
      int col = bn + wc + j * 16 + lc;
      if (col >= Nreal) continue;
      float bb = bias ? bias[col] : 0.f;
#pragma unroll
      for (int r = 0; r < 4; ++r) {
        int row = bm + wr + i * 16 + lr + r;
        float c = acc[i][j][r] + bb;
        if constexpr (EP == EP_Q) {
          u16* qn = (u16*)out0_; float* qr = (float*)out1_;
          int hh = col / 192, d = col - hh * 192;
          if (d < 128) qn[(size_t)row * 2048 + hh * 128 + d] = f2bf(c);
          else qr[(size_t)row * 1024 + hh * 64 + (d - 128)] = c;
        } else if constexpr (EP == EP_DKV) {
          u16* ckv = (u16*)out0_; float* nkv = (float*)out1_; float* kr = (float*)out2_;
          if (col < 512) { ckv[(size_t)row * 512 + col] = f2bf(c); nkv[(size_t)row * 576 + col] = c; }
          else kr[(size_t)row * 64 + (col - 512)] = c;
        } else if constexpr (EP == EP_KV) {
          u16* kn = (u16*)out0_; u16* vv = (u16*)out1_;
          int hh = col >> 8, d = col & 255;
          if (d < 128) kn[(size_t)row * 2048 + hh * 128 + d] = f2bf(c);
          else vv[(size_t)row * 2048 + hh * 128 + (d - 128)] = f2bf(c);
        } else if constexpr (EP == EP_RES) {
          float* out = (float*)out0_;
          out[(size_t)row * Nreal + col] = res[(size_t)row * Nreal + col] + c;
        } else { // EP_GELU
          u16* g = (u16*)out0_;
          float gl = 0.5f * c * (1.f + erff(c * 0.70710678118f));
          g[(size_t)row * Nreal + col] = f2bf(gl);
        }
      }
    }
  }
}

// ---------------- Flash attention ------------------------------------------
// grid (S/64, B*H); Q head dim 192 = [qn 128 | qr 64]; V dim 128. causal.
__global__ __launch_bounds__(256) void k_attn(
    const u16* __restrict__ qn, const float* __restrict__ qr,
    const u16* __restrict__ kn, const float* __restrict__ kr,
    const u16* __restrict__ v, u16* __restrict__ o) {
  __shared__ u16 Qs[64 * 192];
  __shared__ u16 Ks[64 * 192];
  __shared__ u16 Vt[128 * 64];
  __shared__ u16 Ps[64 * 64];
  const int qt = blockIdx.x;
  const int b = blockIdx.y >> 4, h = blockIdx.y & 15;
  const int tid = threadIdx.x, w = tid >> 6, lane = tid & 63;
  const size_t mb = (size_t)b * 2048;
  const float sc2 = 0.07216878365f * 1.4426950408f; // 1/sqrt(192) * log2(e)
  const int lr = (lane >> 4) * 4, lc = lane & 15, ka = (lane >> 4) * 8;

  for (int idx = tid; idx < 64 * 24; idx += 256) {
    int r = idx / 24, c = idx - (idx / 24) * 24;
    size_t m = mb + (size_t)qt * 64 + r;
    if (c < 16) {
      *(int4*)&Qs[r * 192 + c * 8] = *(const int4*)&qn[m * 2048 + h * 128 + c * 8];
    } else {
      const float* s = &qr[m * 1024 + h * 64 + (c - 16) * 8];
      u16 t[8] __attribute__((aligned(16)));
#pragma unroll
      for (int j = 0; j < 8; ++j) t[j] = f2bf(s[j]);
      *(int4*)&Qs[r * 192 + c * 8] = *(int4*)t;
    }
  }

  float m2[4] = {-1e30f, -1e30f, -1e30f, -1e30f};
  float l2[4] = {0.f, 0.f, 0.f, 0.f};
  f32x4 of[8] = {};

  for (int t = 0; t <= qt; ++t) {
    __syncthreads();
    for (int idx = tid; idx < 64 * 24; idx += 256) {
      int r = idx / 24, c = idx - (idx / 24) * 24;
      size_t m = mb + (size_t)t * 64 + r;
      if (c < 16) {
        *(int4*)&Ks[r * 192 + c * 8] = *(const int4*)&kn[m * 2048 + h * 128 + c * 8];
      } else {
        const float* s = &kr[m * 64 + (c - 16) * 8];
        u16 tt[8] __attribute__((aligned(16)));
#pragma unroll
        for (int j = 0; j < 8; ++j) tt[j] = f2bf(s[j]);
        *(int4*)&Ks[r * 192 + c * 8] = *(int4*)tt;
      }
    }
    for (int idx = tid; idx < 64 * 16; idx += 256) {
      int r = idx >> 4, c = idx & 15;
      size_t m = mb + (size_t)t * 64 + r;
      int4 pk = *(const int4*)&v[m * 2048 + h * 128 + c * 8];
      u16* pv = (u16*)&pk;
#pragma unroll
      for (int j = 0; j < 8; ++j) Vt[(c * 8 + j) * 64 + r] = pv[j];
    }
    __syncthreads();

    f32x4 sf[4] = {};
#pragma unroll
    for (int ks = 0; ks < 6; ++ks) {
      bf16x8 aq = *(const bf16x8*)&Qs[(w * 16 + lc) * 192 + ks * 32 + ka];
#pragma unroll
      for (int j = 0; j < 4; ++j) {
        bf16x8 bk = *(const bf16x8*)&Ks[(j * 16 + lc) * 192 + ks * 32 + ka];
        sf[j] = __builtin_amdgcn_mfma_f32_16x16x32_bf16(aq, bk, sf[j], 0, 0, 0);
      }
    }

    float s2[4][4];
#pragma unroll
    for (int j = 0; j < 4; ++j)
#pragma unroll
      for (int r = 0; r < 4; ++r) {
        float x_ = sf[j][r] * sc2;
        if (t == qt) {
          int colg = t * 64 + j * 16 + lc;
          int rowg = qt * 64 + w * 16 + lr + r;
          if (colg > rowg) x_ = -1e30f;
        }
        s2[j][r] = x_;
      }
    float rm[4], fpr[4], ps[4];
#pragma unroll
    for (int r = 0; r < 4; ++r)
      rm[r] = fmaxf(fmaxf(s2[0][r], s2[1][r]), fmaxf(s2[2][r], s2[3][r]));
#pragma unroll
    for (int msk = 1; msk < 16; msk <<= 1)
#pragma unroll
      for (int r = 0; r < 4; ++r) rm[r] = fmaxf(rm[r], __shfl_xor(rm[r], msk));
#pragma unroll
    for (int r = 0; r < 4; ++r) {
      float mn = fmaxf(m2[r], rm[r]);
      fpr[r] = exp2f(m2[r] - mn);
      m2[r] = mn;
      ps[r] = 0.f;
    }
#pragma unroll
    for (int j = 0; j < 4; ++j)
#pragma unroll
      for (int r = 0; r < 4; ++r) {
        float p = exp2f(s2[j][r] - m2[r]);
        ps[r] += p;
        Ps[(w * 16 + lr + r) * 64 + j * 16 + lc] = f2bf(p);
      }
#pragma unroll
    for (int msk = 1; msk < 16; msk <<= 1)
#pragma unroll
      for (int r = 0; r < 4; ++r) ps[r] += __shfl_xor(ps[r], msk);
#pragma unroll
    for (int r = 0; r < 4; ++r) l2[r] = l2[r] * fpr[r] + ps[r];
#pragma unroll
    for (int nb = 0; nb < 8; ++nb)
#pragma unroll
      for (int r = 0; r < 4; ++r) of[nb][r] *= fpr[r];
    __syncthreads();

#pragma unroll
    for (int ks = 0; ks < 2; ++ks) {
      bf16x8 ap = *(const bf16x8*)&Ps[(w * 16 + lc) * 64 + ks * 32 + ka];
#pragma unroll
      for (int nb = 0; nb < 8; ++nb) {
        bf16x8 bvv = *(const bf16x8*)&Vt[(nb * 16 + lc) * 64 + ks * 32 + ka];
        of[nb] = __builtin_amdgcn_mfma_f32_16x16x32_bf16(ap, bvv, of[nb], 0, 0, 0);
      }
    }
  }

#pragma unroll
  for (int r = 0; r < 4; ++r) {
    float inv = 1.f / l2[r];
    size_t m = mb + (size_t)qt * 64 + w * 16 + lr + r;
#pragma unroll
    for (int nb = 0; nb < 8; ++nb)
      o[m * 2048 + h * 128 + nb * 16 + lc] = f2bf(of[nb][r] * inv);
  }
}

// ---------------- launch ----------------------------------------------------
extern "C" void kernel_launch(void* const* d_in, const int* in_sizes, int n_in,
                              void* d_out, int out_size, void* d_ws, size_t ws_size,
                              hipStream_t stream) {
  const float* x = (const float*)d_in[0];
  const float* ln1w = (const float*)d_in[1];
  const float* ln1b = (const float*)d_in[2];
  const float* ln2w = (const float*)d_in[3];
  const float* ln2b = (const float*)d_in[4];
  const float* wq = (const float*)d_in[5];
  const float* bq = (const float*)d_in[6];
  const float* wdkv = (const float*)d_in[7];
  const float* bdkv = (const float*)d_in[8];
  const float* wkv = (const float*)d_in[9];
  const float* bkv = (const float*)d_in[10];
  const float* wo = (const float*)d_in[11];
  const float* bo = (const float*)d_in[12];
  const float* w1 = (const float*)d_in[13];
  const float* b1 = (const float*)d_in[14];
  const float* w2 = (const float*)d_in[15];
  const float* b2 = (const float*)d_in[16];
  (void)in_sizes; (void)n_in; (void)out_size; (void)ws_size;

  char* ws = (char*)d_ws;
  size_t off = 0;
  auto alloc = [&](size_t bytes) { void* p = ws + off; off += (bytes + 255) & ~(size_t)255; return p; };

  u16* wqT = (u16*)alloc(3072ull * 2048 * 2);
  u16* wdkvT = (u16*)alloc(640ull * 2048 * 2);   // 576 real rows, padded to 640
  u16* wkvT = (u16*)alloc(4096ull * 512 * 2);
  u16* woT = (u16*)alloc(2048ull * 2048 * 2);
  u16* w1T = (u16*)alloc(8192ull * 2048 * 2);
  u16* w2T = (u16*)alloc(2048ull * 8192 * 2);
  u16* hbuf = (u16*)alloc(4096ull * 2048 * 2);   // LN1 out; reused for LN2 out
  float* cosT = (float*)alloc(2048ull * 32 * 4);
  float* sinT = (float*)alloc(2048ull * 32 * 4);
  u16* obuf = (u16*)alloc(4096ull * 2048 * 2);
  char* G0 = ws + off;                           // FFN g overlays the region below
  u16* qnb = (u16*)alloc(4096ull * 2048 * 2);
  float* qrb = (float*)alloc(4096ull * 1024 * 4);
  u16* ckvb = (u16*)alloc(4096ull * 512 * 2);
  float* krb = (float*)alloc(4096ull * 64 * 4);
  u16* knb = (u16*)alloc(4096ull * 2048 * 2);
  u16* vb = (u16*)alloc(4096ull * 2048 * 2);
  u16* gb = (u16*)G0;                            // 67.1MB <= 72.3MB region

  float* xout = (float*)d_out;                   // [4096][2048]
  float* nkv = xout + 4096ull * 2048;            // [4096][576]

  dim3 blk(256);
  k_transpose_bf16<<<dim3(64, 96), blk, 0, stream>>>(wq, wqT, 2048, 3072);
  k_transpose_bf16<<<dim3(64, 18), blk, 0, stream>>>(wdkv, wdkvT, 2048, 576);
  k_transpose_bf16<<<dim3(16, 128), blk, 0, stream>>>(wkv, wkvT, 512, 4096);
  k_transpose_bf16<<<dim3(64, 64), blk, 0, stream>>>(wo, woT, 2048, 2048);
  k_transpose_bf16<<<dim3(64, 256), blk, 0, stream>>>(w1, w1T, 2048, 8192);
  k_transpose_bf16<<<dim3(256, 64), blk, 0, stream>>>(w2, w2T, 8192, 2048);
  k_rope_table<<<dim3(256), blk, 0, stream>>>(cosT, sinT);
  k_ln<<<dim3(4096), blk, 0, stream>>>(x, ln1w, ln1b, hbuf);
  k_gemm<EP_Q><<<dim3(24, 32), blk, 0, stream>>>(hbuf, wqT, bq, 2048, 3072, qnb, qrb, nullptr, nullptr);
  k_gemm<EP_DKV><<<dim3(5, 32), blk, 0, stream>>>(hbuf, wdkvT, bdkv, 2048, 576, ckvb, nkv, krb, nullptr);
  k_rope_q<<<dim3(8192), blk, 0, stream>>>(qrb, cosT, sinT);
  k_rope_k<<<dim3(512), blk, 0, stream>>>(krb, cosT, sinT, nkv);
  k_gemm<EP_KV><<<dim3(32, 32), blk, 0, stream>>>(ckvb, wkvT, bkv, 512, 4096, knb, vb, nullptr, nullptr);
  k_attn<<<dim3(32, 32), blk, 0, stream>>>(qnb, qrb, knb, krb, vb, obuf);
  k_gemm<EP_RES><<<dim3(16, 32), blk, 0, stream>>>(obuf, woT, bo, 2048, 2048, xout, nullptr, nullptr, x);
  k_ln<<<dim3(4096), blk, 0, stream>>>(xout, ln2w, ln2b, hbuf);
  k_gemm<EP_GELU><<<dim3(64, 32), blk, 0, stream>>>(hbuf, w1T, b1, 2048, 8192, gb, nullptr, nullptr, nullptr);
  k_gemm<EP_RES><<<dim3(16, 32), blk, 0, stream>>>(gb, w2T, b2, 8192, 2048, xout, nullptr, nullptr, xout);
}

// Round 2
// 1319.463 us; speedup vs baseline: 1.1079x; 1.1079x over previous
//
#include <hip/hip_runtime.h>
#include <hip/hip_bf16.h>

// MLA transformer block on MI355X. Round 2: attention LDS bank-conflict fix
// (padded strides 200/72), conflict-free V transpose staging, reversed causal
// dispatch order. GEMMs unchanged (m97 structure).

typedef short bf16x8 __attribute__((ext_vector_type(8)));
typedef float f32x4 __attribute__((ext_vector_type(4)));
typedef unsigned short u16;

#define BM 128
#define BN 128
#define BK 32

__device__ __forceinline__ u16 f2bf(float f) {
  unsigned int u = __builtin_bit_cast(unsigned int, f);
  u += 0x7FFFu + ((u >> 16) & 1u);
  return (u16)(u >> 16);
}

__device__ __forceinline__ void gload_lds16(const void* g, void* l) {
  __builtin_amdgcn_global_load_lds(
      (const __attribute__((address_space(1))) unsigned int*)(uintptr_t)g,
      (__attribute__((address_space(3))) unsigned int*)(unsigned int)(uintptr_t)l,
      16, 0, 0);
}

// ---------------- transpose + f32->bf16 : out[N][K] = (bf16) in[K][N] ------
__global__ __launch_bounds__(256) void k_transpose_bf16(
    const float* __restrict__ in, u16* __restrict__ out, int K, int N) {
  __shared__ float tile[32][33];
  int k0 = blockIdx.x * 32, n0 = blockIdx.y * 32;
  int tx = threadIdx.x & 31, ty = threadIdx.x >> 5;
#pragma unroll
  for (int i = 0; i < 4; ++i) {
    int k = k0 + ty + i * 8, n = n0 + tx;
    tile[ty + i * 8][tx] = (k < K && n < N) ? in[(size_t)k * N + n] : 0.f;
  }
  __syncthreads();
#pragma unroll
  for (int i = 0; i < 4; ++i) {
    int n = n0 + ty + i * 8, k = k0 + tx;
    if (n < N && k < K) out[(size_t)n * K + k] = f2bf(tile[tx][ty + i * 8]);
  }
}

// ---------------- RoPE tables: cos/sin[s][i], i<32 -------------------------
__global__ void k_rope_table(float* __restrict__ cosT, float* __restrict__ sinT) {
  int idx = blockIdx.x * 256 + threadIdx.x;
  if (idx >= 2048 * 32) return;
  int s = idx >> 5, i = idx & 31;
  float inv = exp2f(-(float)i * 0.41524101186092037f); // log2(10000)/32
  float a = (float)s * inv;
  cosT[idx] = cosf(a);
  sinT[idx] = sinf(a);
}

// ---------------- LayerNorm row=2048, out bf16 -----------------------------
__global__ __launch_bounds__(256) void k_ln(const float* __restrict__ x,
                                            const float* __restrict__ w,
                                            const float* __restrict__ b,
                                            u16* __restrict__ out) {
  const int row = blockIdx.x, tid = threadIdx.x;
  const float* xr = x + (size_t)row * 2048;
  float xv[8];
  *(float4*)&xv[0] = ((const float4*)xr)[tid * 2];
  *(float4*)&xv[4] = ((const float4*)xr)[tid * 2 + 1];
  float s = 0.f, ss = 0.f;
#pragma unroll
  for (int j = 0; j < 8; ++j) { s += xv[j]; ss += xv[j] * xv[j]; }
#pragma unroll
  for (int m_ = 32; m_; m_ >>= 1) { s += __shfl_xor(s, m_); ss += __shfl_xor(ss, m_); }
  __shared__ float red[8];
  const int wv = tid >> 6;
  if ((tid & 63) == 0) { red[wv] = s; red[wv + 4] = ss; }
  __syncthreads();
  s = red[0] + red[1] + red[2] + red[3];
  ss = red[4] + red[5] + red[6] + red[7];
  const float mean = s * (1.f / 2048.f);
  const float rs = rsqrtf(ss * (1.f / 2048.f) - mean * mean + 1e-5f);
  float wv8[8], bv8[8];
  *(float4*)&wv8[0] = ((const float4*)w)[tid * 2];
  *(float4*)&wv8[4] = ((const float4*)w)[tid * 2 + 1];
  *(float4*)&bv8[0] = ((const float4*)b)[tid * 2];
  *(float4*)&bv8[4] = ((const float4*)b)[tid * 2 + 1];
  u16 t[8] __attribute__((aligned(16)));
#pragma unroll
  for (int j = 0; j < 8; ++j) t[j] = f2bf((xv[j] - mean) * rs * wv8[j] + bv8[j]);
  *(int4*)&out[(size_t)row * 2048 + tid * 8] = *(int4*)t;
}

// ---------------- RoPE in-place (fp32) -------------------------------------
__global__ void k_rope_q(float* __restrict__ qr, const float* __restrict__ cosT,
                         const float* __restrict__ sinT) {
  int idx = blockIdx.x * 256 + threadIdx.x; // 4096*16*32
  if (idx >= 4096 * 16 * 32) return;
  int i = idx & 31, rest = idx >> 5;
  int h = rest & 15, m = rest >> 4;
  int s = m & 2047;
  float c = cosT[s * 32 + i], sn = sinT[s * 32 + i];
  float* p = qr + (size_t)m * 1024 + h * 64 + i;
  float x0 = p[0], x1 = p[32];
  p[0] = x0 * c - x1 * sn;
  p[32] = x1 * c + x0 * sn;
}

__global__ void k_rope_k(float* __restrict__ kr, const float* __restrict__ cosT,
                         const float* __restrict__ sinT, float* __restrict__ nkv) {
  int idx = blockIdx.x * 256 + threadIdx.x; // 4096*32
  if (idx >= 4096 * 32) return;
  int i = idx & 31, m = idx >> 5;
  int s = m & 2047;
  float c = cosT[s * 32 + i], sn = sinT[s * 32 + i];
  float* p = kr + (size_t)m * 64 + i;
  float x0 = p[0], x1 = p[32];
  float y0 = x0 * c - x1 * sn;
  float y1 = x1 * c + x0 * sn;
  p[0] = y0; p[32] = y1;
  nkv[(size_t)m * 576 + 512 + i] = y0;
  nkv[(size_t)m * 576 + 544 + i] = y1;
}

// ---------------- GEMM: C[M][N] = A[M][K](bf16) * Bt[N][K]^T + bias --------
enum { EP_Q = 0, EP_DKV = 1, EP_KV = 2, EP_RES = 3, EP_GELU = 4 };

template <int EP>
__global__ __launch_bounds__(256) void k_gemm(
    const u16* __restrict__ A, const u16* __restrict__ Bt,
    const float* __restrict__ bias, int K, int Nreal,
    void* out0_, void* out1_, void* out2_, const float* __restrict__ res) {
  __shared__ u16 As[BM * BK];
  __shared__ u16 Bs[BN * BK];
  const int tid = threadIdx.x;
  const int w = tid >> 6, lane = tid & 63;
  const int bm = blockIdx.y * BM, bn = blockIdx.x * BN;
  const int wr = (w >> 1) * 64, wc = (w & 1) * 64;

  const u16* Ag = A + (size_t)(bm + w * 32 + (lane >> 2)) * K + (lane & 3) * 8;
  const u16* Bg = Bt + (size_t)(bn + w * 32 + (lane >> 2)) * K + (lane & 3) * 8;
  char* lA = (char*)As + w * 2048;
  char* lB = (char*)Bs + w * 2048;

  f32x4 acc[4][4] = {};
  for (int k0 = 0; k0 < K; k0 += BK) {
    __syncthreads();
    gload_lds16(Ag, lA);
    gload_lds16(Ag + 16 * K, lA + 1024);
    gload_lds16(Bg, lB);
    gload_lds16(Bg + 16 * K, lB + 1024);
    Ag += BK; Bg += BK;
    __syncthreads();
    const int ka = (lane >> 4) * 8;
    const int lc = lane & 15;
    bf16x8 av[4], bv[4];
#pragma unroll
    for (int i = 0; i < 4; ++i) av[i] = *(const bf16x8*)&As[(wr + i * 16 + lc) * BK + ka];
#pragma unroll
    for (int j = 0; j < 4; ++j) bv[j] = *(const bf16x8*)&Bs[(wc + j * 16 + lc) * BK + ka];
#pragma unroll
    for (int i = 0; i < 4; ++i)
#pragma unroll
      for (int j = 0; j < 4; ++j)
        acc[i][j] = __builtin_amdgcn_mfma_f32_16x16x32_bf16(av[i], bv[j], acc[i][j], 0, 0, 0);
  }

  const int lr = (lane >> 4) * 4, lc = lane & 15;
#pragma unroll
  for (int i = 0; i < 4; ++i) {
#pragma unroll
    for (int j = 0; j < 4; ++j) {
      int col = bn + wc + j * 16 + lc;
      if (col >= Nreal) continue;
      float bb = bias ? bias[col] : 0.f;
#pragma unroll
      for (int r = 0; r < 4; ++r) {
        int row = bm + wr + i * 16 + lr + r;
        float c = acc[i][j][r] + bb;
        if constexpr (EP == EP_Q) {
          u16* qn = (u16*)out0_; float* qr = (float*)out1_;
          int hh = col / 192, d = col - hh * 192;
          if (d < 128) qn[(size_t)row * 2048 + hh * 128 + d] = f2bf(c);
          else qr[(size_t)row * 1024 + hh * 64 + (d - 128)] = c;
        } else if constexpr (EP == EP_DKV) {
          u16* ckv = (u16*)out0_; float* nkv = (float*)out1_; float* kr = (float*)out2_;
          if (col < 512) { ckv[(size_t)row * 512 + col] = f2bf(c); nkv[(size_t)row * 576 + col] = c; }
          else kr[(size_t)row * 64 + (col - 512)] = c;
        } else if constexpr (EP == EP_KV) {
          u16* kn = (u16*)out0_; u16* vv = (u16*)out1_;
          int hh = col >> 8, d = col & 255;
          if (d < 128) kn[(size_t)row * 2048 + hh * 128 + d] = f2bf(c);
          else vv[(size_t)row * 2048 + hh * 128 + (d - 128)] = f2bf(c);
        } else if constexpr (EP == EP_RES) {
          float* out = (float*)out0_;
          out[(size_t)row * Nreal + col] = res[(size_t)row * Nreal + col] + c;
        } else { // EP_GELU
          u16* g = (u16*)out0_;
          float gl = 0.5f * c * (1.f + erff(c * 0.70710678118f));
          g[(size_t)row * Nreal + col] = f2bf(gl);
        }
      }
    }
  }
}

// ---------------- Flash attention ------------------------------------------
// grid (S/64, B*H); Q head dim 192 = [qn 128 | qr 64]; V dim 128. causal.
// LDS rows padded: Q/K stride 200 u16 (400B), Vt/Ps stride 72 u16 (144B) --
// both are 16 mod 128 bytes so 16-lane fragment reads are 2-way (free).
#define QKS 200
#define VPS 72
__global__ __launch_bounds__(256) void k_attn(
    const u16* __restrict__ qn, const float* __restrict__ qr,
    const u16* __restrict__ kn, const float* __restrict__ kr,
    const u16* __restrict__ v, u16* __restrict__ o) {
  __shared__ u16 Qs[64 * QKS];
  __shared__ u16 Ks[64 * QKS];
  __shared__ u16 Vt[128 * VPS];
  __shared__ u16 Ps[64 * VPS];
  const int qt = (int)gridDim.x - 1 - (int)blockIdx.x; // longest blocks first
  const int b = blockIdx.y >> 4, h = blockIdx.y & 15;
  const int tid = threadIdx.x, w = tid >> 6, lane = tid & 63;
  const size_t mb = (size_t)b * 2048;
  const float sc2 = 0.07216878365f * 1.4426950408f; // 1/sqrt(192) * log2(e)
  const int lr = (lane >> 4) * 4, lc = lane & 15, ka = (lane >> 4) * 8;

  for (int idx = tid; idx < 64 * 24; idx += 256) {
    int r = idx / 24, c = idx - (idx / 24) * 24;
    size_t m = mb + (size_t)qt * 64 + r;
    if (c < 16) {
      *(int4*)&Qs[r * QKS + c * 8] = *(const int4*)&qn[m * 2048 + h * 128 + c * 8];
    } else {
      const float* s = &qr[m * 1024 + h * 64 + (c - 16) * 8];
      u16 t[8] __attribute__((aligned(16)));
#pragma unroll
      for (int j = 0; j < 8; ++j) t[j] = f2bf(s[j]);
      *(int4*)&Qs[r * QKS + c * 8] = *(int4*)t;
    }
  }

  float m2[4] = {-1e30f, -1e30f, -1e30f, -1e30f};
  float l2[4] = {0.f, 0.f, 0.f, 0.f};
  f32x4 of[8] = {};

  for (int t = 0; t <= qt; ++t) {
    __syncthreads();
    for (int idx = tid; idx < 64 * 24; idx += 256) {
      int r = idx / 24, c = idx - (idx / 24) * 24;
      size_t m = mb + (size_t)t * 64 + r;
      if (c < 16) {
        *(int4*)&Ks[r * QKS + c * 8] = *(const int4*)&kn[m * 2048 + h * 128 + c * 8];
      } else {
        const float* s = &kr[m * 64 + (c - 16) * 8];
        u16 tt[8] __attribute__((aligned(16)));
#pragma unroll
        for (int j = 0; j < 8; ++j) tt[j] = f2bf(s[j]);
        *(int4*)&Ks[r * QKS + c * 8] = *(int4*)tt;
      }
    }
    // V transpose staging: lane gathers 8 kv rows for one d, writes one int4.
    for (int idx = tid; idx < 1024; idx += 256) {
      int d = idx & 127, rb = idx >> 7;
      const u16* vp = &v[(mb + (size_t)t * 64 + rb * 8) * 2048 + h * 128 + d];
      u16 t8[8] __attribute__((aligned(16)));
#pragma unroll
      for (int j = 0; j < 8; ++j) t8[j] = vp[j * 2048];
      *(int4*)&Vt[d * VPS + rb * 8] = *(int4*)t8;
    }
    __syncthreads();

    f32x4 sf[4] = {};
#pragma unroll
    for (int ks = 0; ks < 6; ++ks) {
      bf16x8 aq = *(const bf16x8*)&Qs[(w * 16 + lc) * QKS + ks * 32 + ka];
#pragma unroll
      for (int j = 0; j < 4; ++j) {
        bf16x8 bk = *(const bf16x8*)&Ks[(j * 16 + lc) * QKS + ks * 32 + ka];
        sf[j] = __builtin_amdgcn_mfma_f32_16x16x32_bf16(aq, bk, sf[j], 0, 0, 0);
      }
    }

    float s2[4][4];
#pragma unroll
    for (int j = 0; j < 4; ++j)
#pragma unroll
      for (int r = 0; r < 4; ++r) {
        float x_ = sf[j][r] * sc2;
        if (t == qt) {
          int colg = t * 64 + j * 16 + lc;
          int rowg = qt * 64 + w * 16 + lr + r;
          if (colg > rowg) x_ = -1e30f;
        }
        s2[j][r] = x_;
      }
    float rm[4], fpr[4], ps[4];
#pragma unroll
    for (int r = 0; r < 4; ++r)
      rm[r] = fmaxf(fmaxf(s2[0][r], s2[1][r]), fmaxf(s2[2][r], s2[3][r]));
#pragma unroll
    for (int msk = 1; msk < 16; msk <<= 1)
#pragma unroll
      for (int r = 0; r < 4; ++r) rm[r] = fmaxf(rm[r], __shfl_xor(rm[r], msk));
#pragma unroll
    for (int r = 0; r < 4; ++r) {
      float mn = fmaxf(m2[r], rm[r]);
      fpr[r] = exp2f(m2[r] - mn);
      m2[r] = mn;
      ps[r] = 0.f;
    }
#pragma unroll
    for (int j = 0; j < 4; ++j)
#pragma unroll
      for (int r = 0; r < 4; ++r) {
        float p = exp2f(s2[j][r] - m2[r]);
        ps[r] += p;
        Ps[(w * 16 + lr + r) * VPS + j * 16 + lc] = f2bf(p);
      }
#pragma unroll
    for (int msk = 1; msk < 16; msk <<= 1)
#pragma unroll
      for (int r = 0; r < 4; ++r) ps[r] += __shfl_xor(ps[r], msk);
#pragma unroll
    for (int r = 0; r < 4; ++r) l2[r] = l2[r] * fpr[r] + ps[r];
#pragma unroll
    for (int nb = 0; nb < 8; ++nb)
#pragma unroll
      for (int r = 0; r < 4; ++r) of[nb][r] *= fpr[r];
    __syncthreads();

#pragma unroll
    for (int ks = 0; ks < 2; ++ks) {
      bf16x8 ap = *(const bf16x8*)&Ps[(w * 16 + lc) * VPS + ks * 32 + ka];
#pragma unroll
      for (int nb = 0; nb < 8; ++nb) {
        bf16x8 bvv = *(const bf16x8*)&Vt[(nb * 16 + lc) * VPS + ks * 32 + ka];
        of[nb] = __builtin_amdgcn_mfma_f32_16x16x32_bf16(ap, bvv, of[nb], 0, 0, 0);
      }
    }
  }

#pragma unroll
  for (int r = 0; r < 4; ++r) {
    float inv = 1.f / l2[r];
    size_t m = mb + (size_t)qt * 64 + w * 16 + lr + r;
#pragma unroll
    for (int nb = 0; nb < 8; ++nb)
      o[m * 2048 + h * 128 + nb * 16 + lc] = f2bf(of[nb][r] * inv);
  }
}

// ---------------- launch ----------------------------------------------------
extern "C" void kernel_launch(void* const* d_in, const int* in_sizes, int n_in,
                              void* d_out, int out_size, void* d_ws, size_t ws_size,
                              hipStream_t stream) {
  const float* x = (const float*)d_in[0];
  const float* ln1w = (const float*)d_in[1];
  const float* ln1b = (const float*)d_in[2];
  const float* ln2w = (const float*)d_in[3];
  const float* ln2b = (const float*)d_in[4];
  const float* wq = (const float*)d_in[5];
  const float* bq = (const float*)d_in[6];
  const float* wdkv = (const float*)d_in[7];
  const float* bdkv = (const float*)d_in[8];
  const float* wkv = (const float*)d_in[9];
  const float* bkv = (const float*)d_in[10];
  const float* wo = (const float*)d_in[11];
  const float* bo = (const float*)d_in[12];
  const float* w1 = (const float*)d_in[13];
  const float* b1 = (const float*)d_in[14];
  const float* w2 = (const float*)d_in[15];
  const float* b2 = (const float*)d_in[16];
  (void)in_sizes; (void)n_in; (void)out_size; (void)ws_size;

  char* ws = (char*)d_ws;
  size_t off = 0;
  auto alloc = [&](size_t bytes) { void* p = ws + off; off += (bytes + 255) & ~(size_t)255; return p; };

  u16* wqT = (u16*)alloc(3072ull * 2048 * 2);
  u16* wdkvT = (u16*)alloc(640ull * 2048 * 2);   // 576 real rows, padded to 640
  u16* wkvT = (u16*)alloc(4096ull * 512 * 2);
  u16* woT = (u16*)alloc(2048ull * 2048 * 2);
  u16* w1T = (u16*)alloc(8192ull * 2048 * 2);
  u16* w2T = (u16*)alloc(2048ull * 8192 * 2);
  u16* hbuf = (u16*)alloc(4096ull * 2048 * 2);   // LN1 out; reused for LN2 out
  float* cosT = (float*)alloc(2048ull * 32 * 4);
  float* sinT = (float*)alloc(2048ull * 32 * 4);
  u16* obuf = (u16*)alloc(4096ull * 2048 * 2);
  char* G0 = ws + off;                           // FFN g overlays the region below
  u16* qnb = (u16*)alloc(4096ull * 2048 * 2);
  float* qrb = (float*)alloc(4096ull * 1024 * 4);
  u16* ckvb = (u16*)alloc(4096ull * 512 * 2);
  float* krb = (float*)alloc(4096ull * 64 * 4);
  u16* knb = (u16*)alloc(4096ull * 2048 * 2);
  u16* vb = (u16*)alloc(4096ull * 2048 * 2);
  u16* gb = (u16*)G0;                            // 67.1MB <= 72.3MB region

  float* xout = (float*)d_out;                   // [4096][2048]
  float* nkv = xout + 4096ull * 2048;            // [4096][576]

  dim3 blk(256);
  k_transpose_bf16<<<dim3(64, 96), blk, 0, stream>>>(wq, wqT, 2048, 3072);
  k_transpose_bf16<<<dim3(64, 18), blk, 0, stream>>>(wdkv, wdkvT, 2048, 576);
  k_transpose_bf16<<<dim3(16, 128), blk, 0, stream>>>(wkv, wkvT, 512, 4096);
  k_transpose_bf16<<<dim3(64, 64), blk, 0, stream>>>(wo, woT, 2048, 2048);
  k_transpose_bf16<<<dim3(64, 256), blk, 0, stream>>>(w1, w1T, 2048, 8192);
  k_transpose_bf16<<<dim3(256, 64), blk, 0, stream>>>(w2, w2T, 8192, 2048);
  k_rope_table<<<dim3(256), blk, 0, stream>>>(cosT, sinT);
  k_ln<<<dim3(4096), blk, 0, stream>>>(x, ln1w, ln1b, hbuf);
  k_gemm<EP_Q><<<dim3(24, 32), blk, 0, stream>>>(hbuf, wqT, bq, 2048, 3072, qnb, qrb, nullptr, nullptr);
  k_gemm<EP_DKV><<<dim3(5, 32), blk, 0, stream>>>(hbuf, wdkvT, bdkv, 2048, 576, ckvb, nkv, krb, nullptr);
  k_rope_q<<<dim3(8192), blk, 0, stream>>>(qrb, cosT, sinT);
  k_rope_k<<<dim3(512), blk, 0, stream>>>(krb, cosT, sinT, nkv);
  k_gemm<EP_KV><<<dim3(32, 32), blk, 0, stream>>>(ckvb, wkvT, bkv, 512, 4096, knb, vb, nullptr, nullptr);
  k_attn<<<dim3(32, 32), blk, 0, stream>>>(qnb, qrb, knb, krb, vb, obuf);
  k_gemm<EP_RES><<<dim3(16, 32), blk, 0, stream>>>(obuf, woT, bo, 2048, 2048, xout, nullptr, nullptr, x);
  k_ln<<<dim3(4096), blk, 0, stream>>>(xout, ln2w, ln2b, hbuf);
  k_gemm<EP_GELU><<<dim3(64, 32), blk, 0, stream>>>(hbuf, w1T, b1, 2048, 8192, gb, nullptr, nullptr, nullptr);
  k_gemm<EP_RES><<<dim3(16, 32), blk, 0, stream>>>(gb, w2T, b2, 8192, 2048, xout, nullptr, nullptr, xout);
}